// Round 9
// baseline (451.893 us; speedup 1.0000x reference)
//
#include <hip/hip_runtime.h>
#include <math.h>

#define NN 50000
#define NE 1600000
#define KORD 5
#define NB 196          // ceil(NN/256)
#define GE 782          // epi grid: ceil(NN/64)
#define GSP 12500       // spmm grid: ceil(NN/4) (1 wave per node)
#define MT 64           // epi node tile
#define NBK 1563        // ceil(NN/32) destination buckets (32 nodes each)
#define NBP 1600        // padded bucket stride
#define NCH 256         // chunks for edge-pass kernels (fills all CUs)
#define ECH (NE / NCH)  // 6250
#define CVB 1563        // ceil(NN*8/256) cvt blocks
#define NPAD 50048      // padded node-array stride

#define SCALE_D 4194304.0f          // 2^22 degree fixed point
#define INV_SCALE_D (1.0f / 4194304.0f)

typedef _Float16 half8 __attribute__((ext_vector_type(8)));
typedef _Float16 half4v __attribute__((ext_vector_type(4)));
typedef float float4v __attribute__((ext_vector_type(4)));

// ---------------- zero the fixed-point degree array ------------------------
__global__ __launch_bounds__(1024) void k_zero(int* __restrict__ ideg) {
    int i = blockIdx.x * 1024 + threadIdx.x;
    if (i < NN) ideg[i] = 0;
}

// ---------------- deg (global int atomics) + bucket hist (LDS) -------------
// Global native u32 atomicAdd, fire-and-forget (no return -> no wave stall;
// R8 showed atomic-WITH-return cperm at 86us). Deterministic fixed point.
__global__ __launch_bounds__(1024) void k_degbh(const int* __restrict__ ei,
                                                const float* __restrict__ ew,
                                                int* __restrict__ ideg,
                                                int* __restrict__ bh) {
    __shared__ int hist[NBK];
    int ch = blockIdx.x;
    for (int i = threadIdx.x; i < NBK; i += 1024) hist[i] = 0;
    __syncthreads();
    int base = ch * ECH;
    for (int e = base + threadIdx.x; e < base + ECH; e += 1024) {
        int r = ei[e], c = ei[NE + e];
        atomicAdd(&hist[c >> 5], 1);                              // ds_add, native
        atomicAdd(&ideg[r], __float2int_rn(ew[e] * SCALE_D));     // global_atomic_add
    }
    __syncthreads();
    int* outp = bh + ch * NBP;
    for (int b = threadIdx.x; b < NBK; b += 1024) outp[b] = hist[b];
}

// ---------------- btot + dis + cvt fused -----------------------------------
// blocks [0,7): bucket totals; [7,7+NB): dis = rsqrt(deg); rest: x -> fp16
__global__ __launch_bounds__(256) void k_discvt(const int* __restrict__ bh,
                                                int* __restrict__ tot,
                                                const int* __restrict__ ideg,
                                                float* __restrict__ dis,
                                                const float* __restrict__ x,
                                                _Float16* __restrict__ x16) {
    int bid = blockIdx.x;
    if (bid < 7) {
        int b = bid * 256 + threadIdx.x;
        if (b >= NBP) return;
        int s = 0;
        if (b < NBK) {
#pragma unroll 8
            for (int ch = 0; ch < NCH; ch++) s += bh[ch * NBP + b];
        }
        tot[b] = s;
    } else if (bid < 7 + NB) {
        int n = (bid - 7) * 256 + threadIdx.x;
        if (n >= NN) return;
        int s = ideg[n];
        float d = (float)s * INV_SCALE_D;
        dis[n] = s > 0 ? rsqrtf(fmaxf(d, 1e-30f)) : 0.f;
    } else {
        int i = (bid - 7 - NB) * 256 + threadIdx.x;
        if (i < NN * 8) {
            float4 v = ((const float4*)x)[i];
            half4v h = {(_Float16)v.x, (_Float16)v.y, (_Float16)v.z, (_Float16)v.w};
            *(half4v*)(x16 + i * 4) = h;
        }
    }
}

// one block: exclusive scan of bucket totals (UNPADDED) -> off_bk
__global__ __launch_bounds__(1024) void k_bscan1(const int* __restrict__ tot,
                                                 int* __restrict__ off_bk) {
    __shared__ int s[1024];
    int t = threadIdx.x;
    int a0 = (2 * t < NBP) ? tot[2 * t] : 0;
    int a1 = (2 * t + 1 < NBP) ? tot[2 * t + 1] : 0;
    s[t] = a0 + a1;
    __syncthreads();
    for (int d = 1; d < 1024; d <<= 1) {
        int u = (t >= d) ? s[t - d] : 0;
        __syncthreads();
        s[t] += u;
        __syncthreads();
    }
    int excl = (t == 0) ? 0 : s[t - 1];
    if (2 * t < NBK) off_bk[2 * t] = excl;
    if (2 * t + 1 < NBK) off_bk[2 * t + 1] = excl + a0;
    if (t == 1023) off_bk[NBK] = s[1023];
}

// convert bh counts to per-chunk running cursors
__global__ __launch_bounds__(256) void k_bcur(int* __restrict__ bh,
                                              const int* __restrict__ off_bk) {
    int b = blockIdx.x * 256 + threadIdx.x;
    if (b >= NBK) return;
    int run = off_bk[b];
    for (int ch = 0; ch < NCH; ch++) {
        int v = bh[ch * NBP + b];
        bh[ch * NBP + b] = run;
        run += v;
    }
}

// bucket permute: LDS cursors (per-chunk contiguous runs within each bucket).
// record = (r | local_c<<16, weight-bits)
__global__ __launch_bounds__(1024) void k_cperm(const int* __restrict__ ei,
                                                const float* __restrict__ ew,
                                                const float* __restrict__ dis,
                                                const int* __restrict__ bh,
                                                int2* __restrict__ edges1) {
    __shared__ int cur[NBK];
    int ch = blockIdx.x;
    const int* cp = bh + ch * NBP;
    for (int b = threadIdx.x; b < NBK; b += 1024) cur[b] = cp[b];
    __syncthreads();
    int base = ch * ECH;
    for (int e = base + threadIdx.x; e < base + ECH; e += 1024) {
        int r = ei[e], c = ei[NE + e];
        float w = -dis[r] * ew[e] * dis[c];
        int pos = atomicAdd(&cur[c >> 5], 1);   // ds_add_u32, native
        int packed = (int)((unsigned)r | ((unsigned)(c & 31) << 16));
        edges1[pos] = make_int2(packed, __float_as_int(w));
    }
}

// in-bucket counting sort -> node-ordered edges2 + CSR off[] for free.
// All atomics in LDS; reads and writes are bucket-contiguous (~8KB regions).
__global__ __launch_bounds__(256) void k_bsort(const int* __restrict__ off_bk,
                                               const int2* __restrict__ edges1,
                                               int2* __restrict__ edges2,
                                               int* __restrict__ off) {
    __shared__ int hist[32];
    __shared__ int pref[32];
    __shared__ int cur[32];
    int b = blockIdx.x;
    int bs = off_bk[b], be = off_bk[b + 1];
    if (threadIdx.x < 32) hist[threadIdx.x] = 0;
    __syncthreads();
    for (int e = bs + threadIdx.x; e < be; e += 256)
        atomicAdd(&hist[(unsigned)edges1[e].x >> 16], 1);
    __syncthreads();
    if (threadIdx.x == 0) {
        int run = 0;
#pragma unroll
        for (int j = 0; j < 32; j++) { pref[j] = run; run += hist[j]; }
    }
    __syncthreads();
    if (threadIdx.x < 32) {
        int n = b * 32 + threadIdx.x;
        if (n <= NN) off[n] = bs + pref[threadIdx.x];   // off[NN]=NE lands here
        cur[threadIdx.x] = pref[threadIdx.x];
    }
    __syncthreads();
    for (int e = bs + threadIdx.x; e < be; e += 256) {
        int2 rec = edges1[e];
        int cl = (unsigned)rec.x >> 16;
        int pos = bs + atomicAdd(&cur[cl], 1);
        edges2[pos] = make_int2(rec.x & 0xffff, rec.y);
    }
}

// ---------------- spmm: CSR-by-destination, ONE WAVE PER NODE --------------
// Lane = (slot s in [0,8), feature-group fg in [0,8)).  Unroll-4: each lane
// has 4 independent gathers in flight -> one main iteration covers the
// average 32-edge segment.  No LDS / atomics / barriers / divergence.
__global__ __launch_bounds__(256) void k_spmm(const int* __restrict__ off,
                                              const int2* __restrict__ edges,
                                              const _Float16* __restrict__ vin16,
                                              const float* __restrict__ prev,
                                              float* __restrict__ vout,
                                              _Float16* __restrict__ vout16,
                                              float scale) {
    int wid = threadIdx.x >> 6, lane = threadIdx.x & 63;
    int s = lane >> 3, fg = lane & 7;
    int n = blockIdx.x * 4 + wid;
    if (n >= NN) return;
    const half4v* vin4 = (const half4v*)vin16;   // 8 half4 per 32-feature row
    int e0 = off[n], e1 = off[n + 1];
    float a0 = 0.f, a1 = 0.f, a2 = 0.f, a3 = 0.f;
    int e = e0 + s;
    for (; e + 24 < e1; e += 32) {               // 4 edges per lane in flight
        int2 Ra = edges[e];
        int2 Rb = edges[e + 8];
        int2 Rc = edges[e + 16];
        int2 Rd = edges[e + 24];
        half4v ga = vin4[(unsigned)Ra.x * 8u + fg];
        half4v gb = vin4[(unsigned)Rb.x * 8u + fg];
        half4v gc = vin4[(unsigned)Rc.x * 8u + fg];
        half4v gd = vin4[(unsigned)Rd.x * 8u + fg];
        float wa = __int_as_float(Ra.y), wb = __int_as_float(Rb.y);
        float wc = __int_as_float(Rc.y), wd = __int_as_float(Rd.y);
        a0 = fmaf(wa, (float)ga[0], a0); a1 = fmaf(wa, (float)ga[1], a1);
        a2 = fmaf(wa, (float)ga[2], a2); a3 = fmaf(wa, (float)ga[3], a3);
        a0 = fmaf(wb, (float)gb[0], a0); a1 = fmaf(wb, (float)gb[1], a1);
        a2 = fmaf(wb, (float)gb[2], a2); a3 = fmaf(wb, (float)gb[3], a3);
        a0 = fmaf(wc, (float)gc[0], a0); a1 = fmaf(wc, (float)gc[1], a1);
        a2 = fmaf(wc, (float)gc[2], a2); a3 = fmaf(wc, (float)gc[3], a3);
        a0 = fmaf(wd, (float)gd[0], a0); a1 = fmaf(wd, (float)gd[1], a1);
        a2 = fmaf(wd, (float)gd[2], a2); a3 = fmaf(wd, (float)gd[3], a3);
    }
    for (; e < e1; e += 8) {
        int2 Ra = edges[e];
        half4v ga = vin4[(unsigned)Ra.x * 8u + fg];
        float wa = __int_as_float(Ra.y);
        a0 = fmaf(wa, (float)ga[0], a0); a1 = fmaf(wa, (float)ga[1], a1);
        a2 = fmaf(wa, (float)ga[2], a2); a3 = fmaf(wa, (float)ga[3], a3);
    }
#pragma unroll
    for (int m = 8; m < 64; m <<= 1) {
        a0 += __shfl_xor(a0, m);
        a1 += __shfl_xor(a1, m);
        a2 += __shfl_xor(a2, m);
        a3 += __shfl_xor(a3, m);
    }
    if (s == 0) {
        float o0, o1, o2, o3;
        if (prev) {
            float4 p = *(const float4*)(prev + n * 32 + fg * 4);
            o0 = fmaf(scale, a0, -p.x);
            o1 = fmaf(scale, a1, -p.y);
            o2 = fmaf(scale, a2, -p.z);
            o3 = fmaf(scale, a3, -p.w);
        } else {
            o0 = scale * a0; o1 = scale * a1; o2 = scale * a2; o3 = scale * a3;
        }
        if (vout) *(float4*)(vout + n * 32 + fg * 4) = make_float4(o0, o1, o2, o3);
        half4v oh = {(_Float16)o0, (_Float16)o1, (_Float16)o2, (_Float16)o3};
        *(half4v*)(vout16 + n * 32 + fg * 4) = oh;
    }
}

// ---------------- epi1: MFMA GEMM (64 nodes x 64 outs x K=160) + GRU --------
__global__ __launch_bounds__(256) void k_epi1(
    const _Float16* __restrict__ x16, const _Float16* __restrict__ t1,
    const _Float16* __restrict__ t2, const _Float16* __restrict__ t3,
    const _Float16* __restrict__ t4, const float* __restrict__ Wx1,
    const float* __restrict__ bx1, const float* __restrict__ bh1,
    float* __restrict__ h, _Float16* __restrict__ h16) {
    __shared__ _Float16 T[5][MT][40];   // 25.6 KB
    __shared__ _Float16 Wt[64][168];    // 21.5 KB, [n][k]
    int n0 = blockIdx.x * MT;
    const _Float16* bufs[5] = {x16, t1, t2, t3, t4};
#pragma unroll
    for (int b = 0; b < 5; b++) {
        for (int idx = threadIdx.x; idx < MT * 4; idx += 256) {
            int r = idx >> 2, c8 = idx & 3;
            int rr = n0 + r; if (rr >= NN) rr = NN - 1;
            half8 v = *(const half8*)(bufs[b] + rr * 32 + c8 * 8);
            *(half8*)&T[b][r][c8 * 8] = v;
        }
    }
    const float* Wz = Wx1;
    const float* Wh = Wx1 + 2 * KORD * 32 * 32;
    for (int idx = threadIdx.x; idx < 160 * 64; idx += 256) {
        int k = idx >> 6, n = idx & 63;
        int b = k >> 5, i = k & 31;
        float w = (n < 32) ? Wz[b * 1024 + i * 32 + n]
                           : Wh[b * 1024 + i * 32 + (n - 32)];
        Wt[n][k] = (_Float16)w;
    }
    __syncthreads();
    int wave = threadIdx.x >> 6;
    int lane = threadIdx.x & 63;
    int lo = lane & 15, quad = lane >> 4;
    float4v acc[4];
#pragma unroll
    for (int t = 0; t < 4; t++) acc[t] = (float4v){0.f, 0.f, 0.f, 0.f};
#pragma unroll
    for (int b = 0; b < 5; b++) {
        half8 a = *(half8*)&T[b][wave * 16 + lo][quad * 8];
#pragma unroll
        for (int t = 0; t < 4; t++) {
            half8 bf = *(half8*)&Wt[t * 16 + lo][b * 32 + quad * 8];
            acc[t] = __builtin_amdgcn_mfma_f32_16x16x32_f16(a, bf, acc[t], 0, 0, 0);
        }
    }
    int nd_base = n0 + wave * 16 + quad * 4;
#pragma unroll
    for (int t = 0; t < 2; t++) {
        int j = t * 16 + lo;
        float bz = bx1[j] + bh1[j];
        float bhb = bx1[64 + j] + bh1[64 + j];
#pragma unroll
        for (int reg = 0; reg < 4; reg++) {
            int nd = nd_base + reg;
            if (nd < NN) {
                float zz = acc[t][reg] + bz;
                float hh = acc[t + 2][reg] + bhb;
                float z = 1.f / (1.f + __expf(-zz));
                float tt = __expf(-2.f * fabsf(hh));
                float ht = copysignf((1.f - tt) / (1.f + tt), hh);
                float v = fmaxf((1.f - z) * ht, 0.f);
                h[nd * 32 + j] = v;
                h16[nd * 32 + j] = (_Float16)v;
            }
        }
    }
}

// ---------------- epi2: MFMA GEMM (64 x 32 x 160) + GRU + final linear ------
__global__ __launch_bounds__(256) void k_epi2(
    const _Float16* __restrict__ h16, const _Float16* __restrict__ t1,
    const _Float16* __restrict__ t2, const _Float16* __restrict__ t3,
    const _Float16* __restrict__ t4, const float* __restrict__ Wx2,
    const float* __restrict__ bx2, const float* __restrict__ bh2,
    const float* __restrict__ Wl, const float* __restrict__ bl,
    float* __restrict__ out) {
    __shared__ _Float16 T[5][MT][40];   // 25.6 KB
    __shared__ _Float16 Wt[32][168];    // 10.8 KB
    __shared__ float H2[MT][17];
    int n0 = blockIdx.x * MT;
    const _Float16* bufs[5] = {h16, t1, t2, t3, t4};
#pragma unroll
    for (int b = 0; b < 5; b++) {
        for (int idx = threadIdx.x; idx < MT * 4; idx += 256) {
            int r = idx >> 2, c8 = idx & 3;
            int rr = n0 + r; if (rr >= NN) rr = NN - 1;
            half8 v = *(const half8*)(bufs[b] + rr * 32 + c8 * 8);
            *(half8*)&T[b][r][c8 * 8] = v;
        }
    }
    const float* Wz = Wx2;
    const float* Wh = Wx2 + 2 * KORD * 32 * 16;
    for (int idx = threadIdx.x; idx < 160 * 32; idx += 256) {
        int k = idx >> 5, n = idx & 31;
        int b = k >> 5, i = k & 31;
        float w = (n < 16) ? Wz[b * 512 + i * 16 + n]
                           : Wh[b * 512 + i * 16 + (n - 16)];
        Wt[n][k] = (_Float16)w;
    }
    __syncthreads();
    int wave = threadIdx.x >> 6;
    int lane = threadIdx.x & 63;
    int lo = lane & 15, quad = lane >> 4;
    float4v acc[2];
    acc[0] = (float4v){0.f, 0.f, 0.f, 0.f};
    acc[1] = (float4v){0.f, 0.f, 0.f, 0.f};
#pragma unroll
    for (int b = 0; b < 5; b++) {
        half8 a = *(half8*)&T[b][wave * 16 + lo][quad * 8];
#pragma unroll
        for (int t = 0; t < 2; t++) {
            half8 bf = *(half8*)&Wt[t * 16 + lo][b * 32 + quad * 8];
            acc[t] = __builtin_amdgcn_mfma_f32_16x16x32_f16(a, bf, acc[t], 0, 0, 0);
        }
    }
    {
        int j = lo;
        float bz = bx2[j] + bh2[j];
        float bhb = bx2[32 + j] + bh2[32 + j];
        int ndl_base = wave * 16 + quad * 4;
#pragma unroll
        for (int reg = 0; reg < 4; reg++) {
            float zz = acc[0][reg] + bz;
            float hh = acc[1][reg] + bhb;
            float z = 1.f / (1.f + __expf(-zz));
            float tt = __expf(-2.f * fabsf(hh));
            float ht = copysignf((1.f - tt) / (1.f + tt), hh);
            H2[ndl_base + reg][j] = fmaxf((1.f - z) * ht, 0.f);
        }
    }
    __syncthreads();
    for (int idx = threadIdx.x; idx < MT * 12; idx += 256) {
        int n = idx / 12, p = idx % 12;
        int gn = n0 + n;
        if (gn < NN) {
            float o = bl[p];
#pragma unroll
            for (int jj = 0; jj < 16; jj++) o = fmaf(H2[n][jj], Wl[p * 16 + jj], o);
            out[gn * 12 + p] = o;
        }
    }
}

// ---------------- launch ----------------

extern "C" void kernel_launch(void* const* d_in, const int* in_sizes, int n_in,
                              void* d_out, int out_size, void* d_ws, size_t ws_size,
                              hipStream_t stream) {
    const float* x   = (const float*)d_in[0];
    const int*   ei  = (const int*)d_in[1];
    const float* ew  = (const float*)d_in[2];
    const float* Wx1 = (const float*)d_in[3];
    const float* bx1 = (const float*)d_in[4];
    const float* bh1 = (const float*)d_in[6];
    const float* Wx2 = (const float*)d_in[7];
    const float* bx2 = (const float*)d_in[8];
    const float* bh2 = (const float*)d_in[10];
    const float* Wl  = (const float*)d_in[11];
    const float* bl  = (const float*)d_in[12];
    float* out = (float*)d_out;

    float* ws     = (float*)d_ws;
    float* dis    = ws;                         // NPAD floats
    int*   ideg   = (int*)(ws + NPAD);          // NPAD ints
    int*   tot    = ideg + NPAD;                // NBP ints
    int*   off_bk = tot + NBP;                  // NBP ints (uses NBK+1)
    int*   off    = off_bk + NBP;               // NPAD ints (uses NN+1)
    int*   bh     = off + NPAD;                 // NCH*NBP ints
    int2*  edges1 = (int2*)(bh + NCH * NBP);    // NE int2
    int2*  edges2 = edges1 + NE;                // NE int2
    float* T1     = (float*)(edges2 + NE);      // fp32 chain buffers
    float* T2     = T1 + NN * 32;
    float* hb     = T2 + NN * 32;
    _Float16* x16 = (_Float16*)(hb + NN * 32);  // fp16 mirrors
    _Float16* t1h = x16 + NN * 32;
    _Float16* t2h = t1h + NN * 32;
    _Float16* t3h = t2h + NN * 32;
    _Float16* t4h = t3h + NN * 32;
    _Float16* hbh = t4h + NN * 32;

    k_zero  <<<49, 1024, 0, stream>>>(ideg);
    k_degbh <<<NCH, 1024, 0, stream>>>(ei, ew, ideg, bh);
    k_discvt<<<7 + NB + CVB, 256, 0, stream>>>(bh, tot, ideg, dis, x, x16);
    k_bscan1<<<1, 1024, 0, stream>>>(tot, off_bk);
    k_bcur  <<<7, 256, 0, stream>>>(bh, off_bk);
    k_cperm <<<NCH, 1024, 0, stream>>>(ei, ew, dis, bh, edges1);
    k_bsort <<<NBK, 256, 0, stream>>>(off_bk, edges1, edges2, off);

    // ---- cell 1: v = x ----
    k_spmm<<<GSP, 256, 0, stream>>>(off, edges2, x16, nullptr, T1, t1h, 1.f);
    k_spmm<<<GSP, 256, 0, stream>>>(off, edges2, t1h, x,      T2, t2h, 2.f);
    k_spmm<<<GSP, 256, 0, stream>>>(off, edges2, t2h, T1, nullptr, t3h, 2.f);
    k_spmm<<<GSP, 256, 0, stream>>>(off, edges2, t3h, T2, nullptr, t4h, 2.f);
    k_epi1<<<GE, 256, 0, stream>>>(x16, t1h, t2h, t3h, t4h, Wx1, bx1, bh1, hb, hbh);

    // ---- cell 2: v = hb ----
    k_spmm<<<GSP, 256, 0, stream>>>(off, edges2, hbh, nullptr, T1, t1h, 1.f);
    k_spmm<<<GSP, 256, 0, stream>>>(off, edges2, t1h, hb,     T2, t2h, 2.f);
    k_spmm<<<GSP, 256, 0, stream>>>(off, edges2, t2h, T1, nullptr, t3h, 2.f);
    k_spmm<<<GSP, 256, 0, stream>>>(off, edges2, t3h, T2, nullptr, t4h, 2.f);
    k_epi2<<<GE, 256, 0, stream>>>(hbh, t1h, t2h, t3h, t4h, Wx2, bx2, bh2, Wl, bl, out);
}

// Round 10
// 340.776 us; speedup vs baseline: 1.3261x; 1.3261x over previous
//
#include <hip/hip_runtime.h>
#include <math.h>

#define NN 50000
#define NE 1600000
#define KORD 5
#define NB 196          // ceil(NN/256)
#define QTR 12500       // node quarter (k_deg)
#define GE 782          // epi grid: ceil(NN/64)
#define MT 64           // epi node tile
#define NBK 1563        // ceil(NN/32) destination buckets (32 nodes each)
#define NBP 1600        // padded bucket stride
#define NCH 256         // chunks for bucket kernels (fills all CUs)
#define ECH (NE / NCH)  // 6250
#define EC4 (NE / 64)   // 25000 (k_deg chunks)
#define PADE 1800192    // edge buffer capacity (NE + NBK*128, rounded)
#define CVB 1563        // ceil(NN*8/256) cvt blocks

#define SCALE_W 2097152.0f          // 2^21 spmm fixed point
#define INV_SCALE_W (1.0f / 2097152.0f)
#define SCALE_D 4194304.0f          // 2^22 degree fixed point
#define INV_SCALE_D (1.0f / 4194304.0f)

typedef _Float16 half8 __attribute__((ext_vector_type(8)));
typedef _Float16 half4v __attribute__((ext_vector_type(4)));
typedef float float4v __attribute__((ext_vector_type(4)));

// ---------------- deg + bhist fused (both read the edge list) --------------
// LDS-quarter histograms: the only cheap atomic on this chip is LDS int
// (global atomics w/ return = 86us stall [R8]; fire-and-forget scattered
// global atomics = 72us of 64B-line write-back traffic [R9]).
__global__ __launch_bounds__(1024) void k_degbh(const int* __restrict__ ei,
                                                const float* __restrict__ ew,
                                                int* __restrict__ deg_g,
                                                int* __restrict__ bh) {
    __shared__ int sbuf[QTR];   // 50 KB (bhist uses first NBK)
    int bid = blockIdx.x;
    if (bid < 256) {
        int q = bid >> 6, ch = bid & 63;
        for (int i = threadIdx.x; i < QTR; i += 1024) sbuf[i] = 0;
        __syncthreads();
        int base = ch * EC4, lo = q * QTR;
        for (int e = base + threadIdx.x; e < base + EC4; e += 1024) {
            int li = ei[e] - lo;
            if ((unsigned)li < (unsigned)QTR)
                atomicAdd(&sbuf[li], __float2int_rn(ew[e] * SCALE_D));  // ds_add_u32
        }
        __syncthreads();
        int* outp = deg_g + bid * QTR;
        for (int i = threadIdx.x; i < QTR; i += 1024) outp[i] = sbuf[i];
    } else {
        int ch = bid - 256;
        for (int i = threadIdx.x; i < NBK; i += 1024) sbuf[i] = 0;
        __syncthreads();
        const int* cols = ei + NE;
        int base = ch * ECH;
        for (int e = base + threadIdx.x; e < base + ECH; e += 1024)
            atomicAdd(&sbuf[cols[e] >> 5], 1);
        __syncthreads();
        int* outp = bh + ch * NBP;
        for (int b = threadIdx.x; b < NBK; b += 1024) outp[b] = sbuf[b];
    }
}

// ---------------- btot + dis + cvt fused -----------------------------------
__global__ __launch_bounds__(256) void k_btotdiscvt(const int* __restrict__ bh,
                                                    int* __restrict__ tot,
                                                    const int* __restrict__ deg_g,
                                                    float* __restrict__ dis,
                                                    const float* __restrict__ x,
                                                    _Float16* __restrict__ x16) {
    int bid = blockIdx.x;
    if (bid < 7) {
        int b = bid * 256 + threadIdx.x;
        if (b >= NBP) return;
        int s = 0;
        if (b < NBK) {
#pragma unroll 8
            for (int ch = 0; ch < NCH; ch++) s += bh[ch * NBP + b];
        }
        tot[b] = s;
    } else if (bid < 7 + NB) {
        int n = (bid - 7) * 256 + threadIdx.x;
        if (n >= NN) return;
        int q = n / QTR, i = n % QTR;
        const int* p = deg_g + (q * 64) * QTR + i;
        int s = 0;
#pragma unroll
        for (int c = 0; c < 64; c++) s += p[c * QTR];
        float d = (float)s * INV_SCALE_D;
        dis[n] = s > 0 ? rsqrtf(fmaxf(d, 1e-30f)) : 0.f;
    } else {
        int i = (bid - 7 - NB) * 256 + threadIdx.x;
        if (i < NN * 8) {
            float4 v = ((const float4*)x)[i];
            half4v h = {(_Float16)v.x, (_Float16)v.y, (_Float16)v.z, (_Float16)v.w};
            *(half4v*)(x16 + i * 4) = h;
        }
    }
}

// one block: pair-compressed exclusive scan of PADDED totals -> off_bk
// (bucket sizes rounded up to 128 so spmm's 128-edge iterations never split)
__global__ __launch_bounds__(1024) void k_bscan1(const int* __restrict__ tot,
                                                 int* __restrict__ off_bk) {
    __shared__ int s[1024];
    int t = threadIdx.x;
    int a0 = (2 * t < NBP) ? tot[2 * t] : 0;
    int a1 = (2 * t + 1 < NBP) ? tot[2 * t + 1] : 0;
    int p0 = (a0 + 127) & ~127;
    int p1 = (a1 + 127) & ~127;
    s[t] = p0 + p1;
    __syncthreads();
    for (int d = 1; d < 1024; d <<= 1) {
        int u = (t >= d) ? s[t - d] : 0;
        __syncthreads();
        s[t] += u;
        __syncthreads();
    }
    int excl = (t == 0) ? 0 : s[t - 1];
    if (2 * t < NBK) off_bk[2 * t] = excl;
    if (2 * t + 1 < NBK) off_bk[2 * t + 1] = excl + p0;
    if (t == 1023) off_bk[NBK] = s[1023];
}

// convert bh counts to per-chunk running cursors
__global__ __launch_bounds__(256) void k_bcur(int* __restrict__ bh,
                                              const int* __restrict__ off_bk) {
    int b = blockIdx.x * 256 + threadIdx.x;
    if (b >= NBK) return;
    int run = off_bk[b];
    for (int ch = 0; ch < NCH; ch++) {
        int v = bh[ch * NBP + b];
        bh[ch * NBP + b] = run;
        run += v;
    }
}

// coarse permute + pad fill (merged: pad region [off_bk[b]+tot[b], off_bk[b+1])
// is disjoint from the cursor-advanced writes, so no sync is needed).
// record = (r | local_c<<16, weight-bits)
__global__ __launch_bounds__(1024) void k_cperm(const int* __restrict__ ei,
                                                const float* __restrict__ ew,
                                                const float* __restrict__ dis,
                                                const int* __restrict__ bh,
                                                const int* __restrict__ off_bk,
                                                const int* __restrict__ tot,
                                                int2* __restrict__ edges) {
    __shared__ int cur[NBK];
    int ch = blockIdx.x;
    const int* cp = bh + ch * NBP;
    for (int b = threadIdx.x; b < NBK; b += 1024) cur[b] = cp[b];
    // pad fill for this block's bucket stripe (zero-weight sentinel edges)
    for (int b = ch; b < NBK; b += NCH) {
        int start = off_bk[b] + tot[b];
        int end = off_bk[b + 1];
        for (int i = start + threadIdx.x; i < end; i += 1024)
            edges[i] = make_int2(0, 0);   // r=0, c_local=0, w=0.0f
    }
    __syncthreads();
    int base = ch * ECH;
    for (int e = base + threadIdx.x; e < base + ECH; e += 1024) {
        int r = ei[e], c = ei[NE + e];
        float w = -dis[r] * ew[e] * dis[c];
        int pos = atomicAdd(&cur[c >> 5], 1);   // ds_add_u32, native
        int packed = (int)((unsigned)r | ((unsigned)(c & 31) << 16));
        edges[pos] = make_int2(packed, __float_as_int(w));
    }
}

// ---------------- spmm: fp16 half8 gathers, int fixed-point LDS ------------
// 4 lanes per edge; DEPTH-4 pipeline: records prefetched 3 iters ahead,
// gathers issued 2 iters ahead, DS on current.
// NOTE: accumulator must be INT fixed-point — fp32 atomicAdd on LDS lowers to
// a CAS retry loop on hipcc (measured 15x slowdown).  ds_add_u32 is native.
#define SPMM_DS2(C0, W0, G0, C1, W1, G1)                       \
    {                                                          \
        int* a0 = &acc[C0][sub * 8];                           \
        int* a1 = &acc[C1][sub * 8];                           \
        atomicAdd(a0 + 0, __float2int_rn(W0 * (float)G0[0]));  \
        atomicAdd(a0 + 1, __float2int_rn(W0 * (float)G0[1]));  \
        atomicAdd(a0 + 2, __float2int_rn(W0 * (float)G0[2]));  \
        atomicAdd(a0 + 3, __float2int_rn(W0 * (float)G0[3]));  \
        atomicAdd(a0 + 4, __float2int_rn(W0 * (float)G0[4]));  \
        atomicAdd(a0 + 5, __float2int_rn(W0 * (float)G0[5]));  \
        atomicAdd(a0 + 6, __float2int_rn(W0 * (float)G0[6]));  \
        atomicAdd(a0 + 7, __float2int_rn(W0 * (float)G0[7]));  \
        atomicAdd(a1 + 0, __float2int_rn(W1 * (float)G1[0]));  \
        atomicAdd(a1 + 1, __float2int_rn(W1 * (float)G1[1]));  \
        atomicAdd(a1 + 2, __float2int_rn(W1 * (float)G1[2]));  \
        atomicAdd(a1 + 3, __float2int_rn(W1 * (float)G1[3]));  \
        atomicAdd(a1 + 4, __float2int_rn(W1 * (float)G1[4]));  \
        atomicAdd(a1 + 5, __float2int_rn(W1 * (float)G1[5]));  \
        atomicAdd(a1 + 6, __float2int_rn(W1 * (float)G1[6]));  \
        atomicAdd(a1 + 7, __float2int_rn(W1 * (float)G1[7]));  \
    }

__global__ __launch_bounds__(256) void k_spmm(const int* __restrict__ off_bk,
                                              const int2* __restrict__ edges,
                                              const _Float16* __restrict__ vin16,
                                              const float* __restrict__ prev,
                                              float* __restrict__ vout,
                                              _Float16* __restrict__ vout16,
                                              float scale) {
    __shared__ int acc[32][33];
    int b = blockIdx.x;
    {   // init: acc = round(-prev * 2^21), or 0 for the first Chebyshev step
        int nl = threadIdx.x >> 3, s4 = threadIdx.x & 7;
        int n = (b << 5) + nl;
        float4 p = make_float4(0.f, 0.f, 0.f, 0.f);
        if (prev && n < NN) p = ((const float4*)prev)[n * 8 + s4];
        int* a = &acc[nl][s4 * 4];
        a[0] = __float2int_rn(-p.x * SCALE_W);
        a[1] = __float2int_rn(-p.y * SCALE_W);
        a[2] = __float2int_rn(-p.z * SCALE_W);
        a[3] = __float2int_rn(-p.w * SCALE_W);
    }
    __syncthreads();
    int e0 = off_bk[b], e1 = off_bk[b + 1];
    int group = threadIdx.x >> 2, sub = threadIdx.x & 3;
    const half8* vin8 = (const half8*)vin16;   // 4 half8 per 32-feature row
    float wscale = scale * SCALE_W;            // fold scale into weight decode
    int nit = (e1 - e0) >> 7;                  // bucket sizes are 128-multiples
    if (nit > 0) {
        int i = e0 + group;                    // this group's edges: i, i+64
        int2 Ra0 = edges[i], Ra1 = edges[i + 64];
        int2 Rb0 = make_int2(0, 0), Rb1 = make_int2(0, 0);
        int2 Rc0 = make_int2(0, 0), Rc1 = make_int2(0, 0);
        if (nit > 1) { Rb0 = edges[i + 128]; Rb1 = edges[i + 192]; }
        if (nit > 2) { Rc0 = edges[i + 256]; Rc1 = edges[i + 320]; }
        half8 Ga0 = vin8[((unsigned)Ra0.x & 0xffffu) * 4 + sub];
        half8 Ga1 = vin8[((unsigned)Ra1.x & 0xffffu) * 4 + sub];
        half8 Gb0 = {}, Gb1 = {};
        if (nit > 1) {
            Gb0 = vin8[((unsigned)Rb0.x & 0xffffu) * 4 + sub];
            Gb1 = vin8[((unsigned)Rb1.x & 0xffffu) * 4 + sub];
        }
        for (int k = 0; k < nit; k++) {
            int2 Rd0 = make_int2(0, 0), Rd1 = make_int2(0, 0);
            if (k + 3 < nit) { Rd0 = edges[i + 384]; Rd1 = edges[i + 448]; }
            half8 Gc0 = {}, Gc1 = {};
            if (k + 2 < nit) {
                Gc0 = vin8[((unsigned)Rc0.x & 0xffffu) * 4 + sub];
                Gc1 = vin8[((unsigned)Rc1.x & 0xffffu) * 4 + sub];
            }
            int C0 = (unsigned)Ra0.x >> 16, C1 = (unsigned)Ra1.x >> 16;
            float W0 = __int_as_float(Ra0.y) * wscale;
            float W1 = __int_as_float(Ra1.y) * wscale;
            SPMM_DS2(C0, W0, Ga0, C1, W1, Ga1);
            Ra0 = Rb0; Ra1 = Rb1; Rb0 = Rc0; Rb1 = Rc1; Rc0 = Rd0; Rc1 = Rd1;
            Ga0 = Gb0; Ga1 = Gb1; Gb0 = Gc0; Gb1 = Gc1;
            i += 128;
        }
    }
    __syncthreads();
    int base = b << 5;
    int nl = threadIdx.x >> 3, s4 = threadIdx.x & 7;
    int n = base + nl;
    if (n < NN) {
        const int* a = &acc[nl][s4 * 4];
        float4 o = make_float4((float)a[0] * INV_SCALE_W, (float)a[1] * INV_SCALE_W,
                               (float)a[2] * INV_SCALE_W, (float)a[3] * INV_SCALE_W);
        if (vout) ((float4*)vout)[n * 8 + s4] = o;  // fp32 chain (only when read later)
        half4v oh = {(_Float16)o.x, (_Float16)o.y, (_Float16)o.z, (_Float16)o.w};
        *(half4v*)(vout16 + n * 32 + s4 * 4) = oh;  // fp16 gather/epi mirror
    }
}

// ---------------- epi1: MFMA GEMM (64 nodes x 64 outs x K=160) + GRU --------
__global__ __launch_bounds__(256) void k_epi1(
    const _Float16* __restrict__ x16, const _Float16* __restrict__ t1,
    const _Float16* __restrict__ t2, const _Float16* __restrict__ t3,
    const _Float16* __restrict__ t4, const float* __restrict__ Wx1,
    const float* __restrict__ bx1, const float* __restrict__ bh1,
    float* __restrict__ h, _Float16* __restrict__ h16) {
    __shared__ _Float16 T[5][MT][40];   // 25.6 KB
    __shared__ _Float16 Wt[64][168];    // 21.5 KB, [n][k]
    int n0 = blockIdx.x * MT;
    const _Float16* bufs[5] = {x16, t1, t2, t3, t4};
#pragma unroll
    for (int b = 0; b < 5; b++) {
        for (int idx = threadIdx.x; idx < MT * 4; idx += 256) {
            int r = idx >> 2, c8 = idx & 3;
            int rr = n0 + r; if (rr >= NN) rr = NN - 1;
            half8 v = *(const half8*)(bufs[b] + rr * 32 + c8 * 8);
            *(half8*)&T[b][r][c8 * 8] = v;
        }
    }
    const float* Wz = Wx1;
    const float* Wh = Wx1 + 2 * KORD * 32 * 32;
    for (int idx = threadIdx.x; idx < 160 * 64; idx += 256) {
        int k = idx >> 6, n = idx & 63;
        int b = k >> 5, i = k & 31;
        float w = (n < 32) ? Wz[b * 1024 + i * 32 + n]
                           : Wh[b * 1024 + i * 32 + (n - 32)];
        Wt[n][k] = (_Float16)w;
    }
    __syncthreads();
    int wave = threadIdx.x >> 6;
    int lane = threadIdx.x & 63;
    int lo = lane & 15, quad = lane >> 4;
    float4v acc[4];
#pragma unroll
    for (int t = 0; t < 4; t++) acc[t] = (float4v){0.f, 0.f, 0.f, 0.f};
#pragma unroll
    for (int b = 0; b < 5; b++) {
        half8 a = *(half8*)&T[b][wave * 16 + lo][quad * 8];
#pragma unroll
        for (int t = 0; t < 4; t++) {
            half8 bf = *(half8*)&Wt[t * 16 + lo][b * 32 + quad * 8];
            acc[t] = __builtin_amdgcn_mfma_f32_16x16x32_f16(a, bf, acc[t], 0, 0, 0);
        }
    }
    int nd_base = n0 + wave * 16 + quad * 4;
#pragma unroll
    for (int t = 0; t < 2; t++) {
        int j = t * 16 + lo;
        float bz = bx1[j] + bh1[j];
        float bhb = bx1[64 + j] + bh1[64 + j];
#pragma unroll
        for (int reg = 0; reg < 4; reg++) {
            int nd = nd_base + reg;
            if (nd < NN) {
                float zz = acc[t][reg] + bz;
                float hh = acc[t + 2][reg] + bhb;
                float z = 1.f / (1.f + __expf(-zz));
                float tt = __expf(-2.f * fabsf(hh));
                float ht = copysignf((1.f - tt) / (1.f + tt), hh);
                float v = fmaxf((1.f - z) * ht, 0.f);
                h[nd * 32 + j] = v;
                h16[nd * 32 + j] = (_Float16)v;
            }
        }
    }
}

// ---------------- epi2: MFMA GEMM (64 x 32 x 160) + GRU + final linear ------
__global__ __launch_bounds__(256) void k_epi2(
    const _Float16* __restrict__ h16, const _Float16* __restrict__ t1,
    const _Float16* __restrict__ t2, const _Float16* __restrict__ t3,
    const _Float16* __restrict__ t4, const float* __restrict__ Wx2,
    const float* __restrict__ bx2, const float* __restrict__ bh2,
    const float* __restrict__ Wl, const float* __restrict__ bl,
    float* __restrict__ out) {
    __shared__ _Float16 T[5][MT][40];   // 25.6 KB
    __shared__ _Float16 Wt[32][168];    // 10.8 KB
    __shared__ float H2[MT][17];
    int n0 = blockIdx.x * MT;
    const _Float16* bufs[5] = {h16, t1, t2, t3, t4};
#pragma unroll
    for (int b = 0; b < 5; b++) {
        for (int idx = threadIdx.x; idx < MT * 4; idx += 256) {
            int r = idx >> 2, c8 = idx & 3;
            int rr = n0 + r; if (rr >= NN) rr = NN - 1;
            half8 v = *(const half8*)(bufs[b] + rr * 32 + c8 * 8);
            *(half8*)&T[b][r][c8 * 8] = v;
        }
    }
    const float* Wz = Wx2;
    const float* Wh = Wx2 + 2 * KORD * 32 * 16;
    for (int idx = threadIdx.x; idx < 160 * 32; idx += 256) {
        int k = idx >> 5, n = idx & 31;
        int b = k >> 5, i = k & 31;
        float w = (n < 16) ? Wz[b * 512 + i * 16 + n]
                           : Wh[b * 512 + i * 16 + (n - 16)];
        Wt[n][k] = (_Float16)w;
    }
    __syncthreads();
    int wave = threadIdx.x >> 6;
    int lane = threadIdx.x & 63;
    int lo = lane & 15, quad = lane >> 4;
    float4v acc[2];
    acc[0] = (float4v){0.f, 0.f, 0.f, 0.f};
    acc[1] = (float4v){0.f, 0.f, 0.f, 0.f};
#pragma unroll
    for (int b = 0; b < 5; b++) {
        half8 a = *(half8*)&T[b][wave * 16 + lo][quad * 8];
#pragma unroll
        for (int t = 0; t < 2; t++) {
            half8 bf = *(half8*)&Wt[t * 16 + lo][b * 32 + quad * 8];
            acc[t] = __builtin_amdgcn_mfma_f32_16x16x32_f16(a, bf, acc[t], 0, 0, 0);
        }
    }
    {
        int j = lo;
        float bz = bx2[j] + bh2[j];
        float bhb = bx2[32 + j] + bh2[32 + j];
        int ndl_base = wave * 16 + quad * 4;
#pragma unroll
        for (int reg = 0; reg < 4; reg++) {
            float zz = acc[0][reg] + bz;
            float hh = acc[1][reg] + bhb;
            float z = 1.f / (1.f + __expf(-zz));
            float tt = __expf(-2.f * fabsf(hh));
            float ht = copysignf((1.f - tt) / (1.f + tt), hh);
            H2[ndl_base + reg][j] = fmaxf((1.f - z) * ht, 0.f);
        }
    }
    __syncthreads();
    for (int idx = threadIdx.x; idx < MT * 12; idx += 256) {
        int n = idx / 12, p = idx % 12;
        int gn = n0 + n;
        if (gn < NN) {
            float o = bl[p];
#pragma unroll
            for (int jj = 0; jj < 16; jj++) o = fmaf(H2[n][jj], Wl[p * 16 + jj], o);
            out[gn * 12 + p] = o;
        }
    }
}

// ---------------- launch ----------------

extern "C" void kernel_launch(void* const* d_in, const int* in_sizes, int n_in,
                              void* d_out, int out_size, void* d_ws, size_t ws_size,
                              hipStream_t stream) {
    const float* x   = (const float*)d_in[0];
    const int*   ei  = (const int*)d_in[1];
    const float* ew  = (const float*)d_in[2];
    const float* Wx1 = (const float*)d_in[3];
    const float* bx1 = (const float*)d_in[4];
    const float* bh1 = (const float*)d_in[6];
    const float* Wx2 = (const float*)d_in[7];
    const float* bx2 = (const float*)d_in[8];
    const float* bh2 = (const float*)d_in[10];
    const float* Wl  = (const float*)d_in[11];
    const float* bl  = (const float*)d_in[12];
    float* out = (float*)d_out;

    float* ws     = (float*)d_ws;
    float* dis    = ws;                         // 50048 floats
    int*   bh     = (int*)(ws + 50048);         // NCH*NBP = 409600 ints
    int*   tot    = bh + NCH * NBP;             // NBP ints
    int*   off_bk = tot + NBP;                  // NBP ints
    int2*  edges  = (int2*)(off_bk + NBP);      // PADE int2 (padded buckets)
    float* T1     = (float*)(edges + PADE);     // fp32 chain buffers
    float* T2     = T1 + NN * 32;
    float* T3     = T2 + NN * 32;
    float* hb     = T3 + NN * 32;
    _Float16* x16 = (_Float16*)(hb + NN * 32);  // fp16 mirrors
    _Float16* t1h = x16 + NN * 32;
    _Float16* t2h = t1h + NN * 32;
    _Float16* t3h = t2h + NN * 32;
    _Float16* t4h = t3h + NN * 32;
    _Float16* hbh = t4h + NN * 32;
    int*   deg_g  = (int*)T1;  // 256*QTR ints (T1+T2 region, dead before spmm)

    k_degbh     <<<512, 1024, 0, stream>>>(ei, ew, deg_g, bh);
    k_btotdiscvt<<<7 + NB + CVB, 256, 0, stream>>>(bh, tot, deg_g, dis, x, x16);
    k_bscan1    <<<1, 1024, 0, stream>>>(tot, off_bk);
    k_bcur      <<<7, 256, 0, stream>>>(bh, off_bk);
    k_cperm     <<<NCH, 1024, 0, stream>>>(ei, ew, dis, bh, off_bk, tot, edges);

    // ---- cell 1: v = x ----  (T3 fp32 is never read -> skip its write)
    k_spmm<<<NBK, 256, 0, stream>>>(off_bk, edges, x16, nullptr, T1, t1h, 1.f);
    k_spmm<<<NBK, 256, 0, stream>>>(off_bk, edges, t1h, x,      T2, t2h, 2.f);
    k_spmm<<<NBK, 256, 0, stream>>>(off_bk, edges, t2h, T1, nullptr, t3h, 2.f);
    k_spmm<<<NBK, 256, 0, stream>>>(off_bk, edges, t3h, T2, nullptr, t4h, 2.f);
    k_epi1<<<GE, 256, 0, stream>>>(x16, t1h, t2h, t3h, t4h, Wx1, bx1, bh1, hb, hbh);

    // ---- cell 2: v = hb ----
    k_spmm<<<NBK, 256, 0, stream>>>(off_bk, edges, hbh, nullptr, T1, t1h, 1.f);
    k_spmm<<<NBK, 256, 0, stream>>>(off_bk, edges, t1h, hb,     T2, t2h, 2.f);
    k_spmm<<<NBK, 256, 0, stream>>>(off_bk, edges, t2h, T1, nullptr, t3h, 2.f);
    k_spmm<<<NBK, 256, 0, stream>>>(off_bk, edges, t3h, T2, nullptr, t4h, 2.f);
    k_epi2<<<GE, 256, 0, stream>>>(hbh, t1h, t2h, t3h, t4h, Wx2, bx2, bh2, Wl, bl, out);
}